// Round 1
// baseline (375.158 us; speedup 1.0000x reference)
//
#include <hip/hip_runtime.h>
#include <cfloat>

#define NPOS_TOT 32768
#define NE 1024
#define EDIM 256
#define HW 1024
#define BATCH_STRIDE (EDIM * HW)   // 262144
#define TOTAL_ELEMS 8388608

// workspace layout (bytes)
#define EMT_OFF   0                         // float[256*1024] = 1 MB (embT, k-major)
#define ENORM_OFF (1 << 20)                 // float[1024]
#define IDX_OFF   (ENORM_OFF + 4096)        // int[32768]
#define HIST_OFF  (IDX_OFF + 131072)        // int[1024]
#define LOSS_OFF  (HIST_OFF + 4096)         // float accumulator

// ---------------------------------------------------------------------------
// Kernel A: enorm[k] = ||emb[k]||^2  and  embT[c*1024 + k] = emb[k*256 + c]
// grid 4 x 256 threads, one code row per thread. embT writes are coalesced
// across lanes (consecutive k); loads are per-lane rows (1 MB total, cheap).
// ---------------------------------------------------------------------------
__global__ void prep_kernel(const float* __restrict__ emb,
                            float* __restrict__ embT,
                            float* __restrict__ enorm) {
    int k = blockIdx.x * 256 + threadIdx.x;      // 0..1023
    const float4* emb4 = (const float4*)emb;
    float s = 0.f;
    for (int c4 = 0; c4 < 64; ++c4) {
        float4 v = emb4[k * 64 + c4];
        s += v.x * v.x + v.y * v.y + v.z * v.z + v.w * v.w;
        int c = c4 * 4;
        embT[(c + 0) * NE + k] = v.x;
        embT[(c + 1) * NE + k] = v.y;
        embT[(c + 2) * NE + k] = v.z;
        embT[(c + 3) * NE + k] = v.w;
    }
    enorm[k] = s;
}

// ---------------------------------------------------------------------------
// Kernel B: per block: 64 positions x 1024 codes argmin of ||e||^2 - 2 z.e
// grid 512 (= 32 batches * 16 position tiles), 256 threads (16x16).
// LDS: As[64k x 64m] 16 KB + Bs[64k x 64n] 16 KB + enorm 4 KB = 36 KB.
// Thread (tm,tn) computes a 4x4 micro-tile; tie-break = lowest code index.
// ---------------------------------------------------------------------------
__global__ __launch_bounds__(256, 4) void argmin_kernel(
        const float* __restrict__ z, const float* __restrict__ embT,
        const float* __restrict__ enorm, int* __restrict__ idxOut) {
    __shared__ float As[64 * 64];
    __shared__ float Bs[64 * 64];
    __shared__ float Ens[NE];
    int t = threadIdx.x;
    int bid = blockIdx.x;
    int b = bid >> 4;
    int p0 = (bid & 15) * 64;
    const float4* zb4 = (const float4*)(z + (size_t)b * BATCH_STRIDE);
    const float4* eT4 = (const float4*)embT;
    float4* As4 = (float4*)As;
    float4* Bs4 = (float4*)Bs;
    for (int j = t; j < NE; j += 256) Ens[j] = enorm[j];

    int tm = t & 15, tn = t >> 4;
    float bestv[4];
    int   besti[4];
#pragma unroll
    for (int i = 0; i < 4; ++i) { bestv[i] = FLT_MAX; besti[i] = 0x7fffffff; }

    for (int nt = 0; nt < 16; ++nt) {
        int n0 = nt * 64;
        float acc[4][4] = {};
        for (int kc = 0; kc < 4; ++kc) {
            __syncthreads();   // previous tile consumed
#pragma unroll
            for (int it = 0; it < 4; ++it) {
                int f4 = t + it * 256;            // 0..1023 float4 slots
                int kk = f4 >> 4, m4 = f4 & 15;
                int c = kc * 64 + kk;             // global k index
                As4[f4] = zb4[c * 256 + (p0 >> 2) + m4];
                Bs4[f4] = eT4[c * 256 + (n0 >> 2) + m4];
            }
            __syncthreads();
#pragma unroll 8
            for (int kk = 0; kk < 64; ++kk) {
                float4 a  = As4[kk * 16 + tm];
                float4 bb = Bs4[kk * 16 + tn];
                float av[4] = {a.x, a.y, a.z, a.w};
                float bv[4] = {bb.x, bb.y, bb.z, bb.w};
#pragma unroll
                for (int i = 0; i < 4; ++i)
#pragma unroll
                    for (int j = 0; j < 4; ++j)
                        acc[i][j] += av[i] * bv[j];
            }
        }
        // fold this code tile into the running argmin
#pragma unroll
        for (int j = 0; j < 4; ++j) {
            int code = n0 + tn * 4 + j;
            float en = Ens[code];
#pragma unroll
            for (int i = 0; i < 4; ++i) {
                float d = en - 2.f * acc[i][j];
                if (d < bestv[i]) { bestv[i] = d; besti[i] = code; }
            }
        }
    }

    // cross-tn reduction (alias tile LDS)
    __syncthreads();
    float* red_v = Bs;
    int*   red_i = (int*)As;
#pragma unroll
    for (int i = 0; i < 4; ++i) { red_v[t * 4 + i] = bestv[i]; red_i[t * 4 + i] = besti[i]; }
    __syncthreads();
    if (t < 16) {
        for (int i = 0; i < 4; ++i) {
            float bv = FLT_MAX; int bi = 0x7fffffff;
            for (int tn2 = 0; tn2 < 16; ++tn2) {
                int src = (tn2 * 16 + t) * 4 + i;
                float v = red_v[src]; int ii = red_i[src];
                if (v < bv || (v == bv && ii < bi)) { bv = v; bi = ii; }
            }
            idxOut[b * HW + p0 + t * 4 + i] = bi;
        }
    }
}

// ---------------------------------------------------------------------------
// Kernel C: z_q gather + loss partial + histogram.
// grid 512 x 256 threads; block = 64 positions x 256 channels.
// LDS Es[c][p] (c-major, p contiguous) = exactly 64 KB, conflict-free reads.
// ---------------------------------------------------------------------------
__global__ __launch_bounds__(256, 2) void output_kernel(
        const float* __restrict__ z, const float* __restrict__ emb,
        const int* __restrict__ idxArr, float* __restrict__ zq,
        int* __restrict__ hist, float* __restrict__ lossAcc) {
    __shared__ float Es[EDIM * 64];   // Es[c*64 + p]
    int t = threadIdx.x;
    int n0 = blockIdx.x * 64;
    int b = n0 >> 10;
    int p0 = n0 & 1023;

    if (t < 64) atomicAdd(&hist[idxArr[n0 + t]], 1);

    // stage the 64 selected embedding rows, transposed to Es[c][p]
    {
        int r = t >> 2, q = t & 3;                 // row (position), quarter
        int kr = idxArr[n0 + r];
        const float4* emb4 = (const float4*)emb;
#pragma unroll
        for (int u = 0; u < 16; ++u) {
            float4 v = emb4[kr * 64 + q * 16 + u];
            int c = (q * 16 + u) * 4;
            Es[(c + 0) * 64 + r] = v.x;
            Es[(c + 1) * 64 + r] = v.y;
            Es[(c + 2) * 64 + r] = v.z;
            Es[(c + 3) * 64 + r] = v.w;
        }
    }
    __syncthreads();

    int p = t & 63, c4 = t >> 6;
    const float* zb = z + (size_t)b * BATCH_STRIDE;
    float*      zqb = zq + (size_t)b * BATCH_STRIDE;
    float ls = 0.f;
    for (int cc = 0; cc < 64; ++cc) {
        int c = c4 * 64 + cc;
        float zv = zb[c * HW + p0 + p];
        float ev = Es[c * 64 + p];
        zqb[c * HW + p0 + p] = ev;
        float df = ev - zv;
        ls += df * df;
    }
#pragma unroll
    for (int off = 32; off; off >>= 1) ls += __shfl_down(ls, off, 64);
    if ((t & 63) == 0) atomicAdd(lossAcc, ls);
}

// ---------------------------------------------------------------------------
// Kernel D: finalize loss + perplexity into d_out tail.
// ---------------------------------------------------------------------------
__global__ void finalize_kernel(const int* __restrict__ hist,
                                const float* __restrict__ lossAcc,
                                float* __restrict__ out) {
    __shared__ float wsum[4];
    int t = threadIdx.x;
    float s = 0.f;
    for (int j = t; j < NE; j += 256) {
        float p = (float)hist[j] * (1.0f / 32768.0f);
        s += p * logf(p + 1e-10f);
    }
#pragma unroll
    for (int off = 32; off; off >>= 1) s += __shfl_down(s, off, 64);
    if ((t & 63) == 0) wsum[t >> 6] = s;
    __syncthreads();
    if (t == 0) {
        float S = wsum[0] + wsum[1] + wsum[2] + wsum[3];
        out[TOTAL_ELEMS]     = 1.25f * lossAcc[0] / (float)TOTAL_ELEMS;
        out[TOTAL_ELEMS + 1] = expf(-S);
    }
}

extern "C" void kernel_launch(void* const* d_in, const int* in_sizes, int n_in,
                              void* d_out, int out_size, void* d_ws, size_t ws_size,
                              hipStream_t stream) {
    (void)in_sizes; (void)n_in; (void)out_size; (void)ws_size;
    const float* z   = (const float*)d_in[0];
    const float* emb = (const float*)d_in[1];
    float* out = (float*)d_out;
    char* ws = (char*)d_ws;
    float* embT   = (float*)(ws + EMT_OFF);
    float* enorm  = (float*)(ws + ENORM_OFF);
    int*   idxArr = (int*)(ws + IDX_OFF);
    int*   hist   = (int*)(ws + HIST_OFF);
    float* lossAcc = (float*)(ws + LOSS_OFF);

    hipMemsetAsync(ws + HIST_OFF, 0, 4096 + 16, stream);   // hist + loss accum
    prep_kernel<<<4, 256, 0, stream>>>(emb, embT, enorm);
    argmin_kernel<<<512, 256, 0, stream>>>(z, embT, enorm, idxArr);
    output_kernel<<<512, 256, 0, stream>>>(z, emb, idxArr, out, hist, lossAcc);
    finalize_kernel<<<1, 256, 0, stream>>>(hist, lossAcc, out);
}

// Round 2
// 199.754 us; speedup vs baseline: 1.8781x; 1.8781x over previous
//
#include <hip/hip_runtime.h>
#include <cfloat>

typedef __attribute__((ext_vector_type(8))) short short8;
typedef __attribute__((ext_vector_type(4))) float f32x4;

#define NE 1024
#define EDIM 256
#define HW 1024
#define BSTRIDE (EDIM * HW)        // 262144
#define TOTAL 8388608

// workspace layout (bytes)
#define EMBB_OFF  0                        // ushort[1024*256] bf16 = 512 KB
#define ENORM_OFF (512 * 1024)             // float[1024]
#define IDX_OFF   (ENORM_OFF + 4096)       // int[32768]
#define HIST_OFF  (IDX_OFF + 131072)       // int[1024]
#define LOSS_OFF  (HIST_OFF + 4096)        // float accumulator

// round-to-nearest-even fp32 -> bf16 bits (inputs are finite)
__device__ __forceinline__ unsigned short f2bf(float x) {
    unsigned u = __builtin_bit_cast(unsigned, x);
    return (unsigned short)((u + 0x7fffu + ((u >> 16) & 1u)) >> 16);
}

// ---------------------------------------------------------------------------
// P: emb fp32 [1024][256] -> embB bf16 rows (k-contiguous) + enorm fp32
// ---------------------------------------------------------------------------
__global__ void prep_emb(const float* __restrict__ emb,
                         unsigned short* __restrict__ embB,
                         float* __restrict__ enorm) {
    int k = blockIdx.x * 256 + threadIdx.x;          // code row 0..1023
    const float4* e4 = (const float4*)(emb + (size_t)k * EDIM);
    float s = 0.f;
    for (int i = 0; i < 32; ++i) {                   // 8 floats / iter
        float4 a = e4[2 * i], b = e4[2 * i + 1];
        s += a.x * a.x + a.y * a.y + a.z * a.z + a.w * a.w
           + b.x * b.x + b.y * b.y + b.z * b.z + b.w * b.w;
        short8 v;
        v[0] = (short)f2bf(a.x); v[1] = (short)f2bf(a.y);
        v[2] = (short)f2bf(a.z); v[3] = (short)f2bf(a.w);
        v[4] = (short)f2bf(b.x); v[5] = (short)f2bf(b.y);
        v[6] = (short)f2bf(b.z); v[7] = (short)f2bf(b.w);
        *(short8*)&embB[(size_t)k * EDIM + i * 8] = v;
    }
    enorm[k] = s;
}

// ---------------------------------------------------------------------------
// Q: MFMA argmin. Block = 32 positions; wave w owns codes [256w, 256w+256).
// A (32 pos x 256 k) transposed to bf16 in LDS once (pitch 264 -> clean b128),
// held in registers; B fragments streamed from L2 (embB is 512 KB, L2-hot).
// D[m][n]: m=row=(lane>>4)*4+reg (position), n=col=lane&15 (code).
// ---------------------------------------------------------------------------
__global__ __launch_bounds__(256, 4) void argmin_kernel(
        const float* __restrict__ z, const unsigned short* __restrict__ embB,
        const float* __restrict__ enorm, int* __restrict__ idxOut) {
    __shared__ __align__(16) unsigned short As[32 * 264];
    __shared__ float rv[4 * 32];
    __shared__ int   ri[4 * 32];
    int t = threadIdx.x;
    int m0 = blockIdx.x * 32;                 // global position base
    int b = m0 >> 10, pb = m0 & 1023;

    {   // stage + transpose + bf16-convert the A tile
        int p = t & 31, c2 = t >> 5;          // 32 positions x 8 c-groups
        const float* zp = z + (size_t)b * BSTRIDE + pb + p;
        for (int cc = 0; cc < 32; ++cc) {
            int c = c2 * 32 + cc;
            As[p * 264 + c] = f2bf(zp[(size_t)c * HW]);
        }
    }
    __syncthreads();

    int w = t >> 6, l = t & 63, lm = l & 15, q = l >> 4;

    short8 A[2][8];
#pragma unroll
    for (int s = 0; s < 2; ++s)
#pragma unroll
        for (int ks = 0; ks < 8; ++ks)
            A[s][ks] = *(const short8*)&As[(s * 16 + lm) * 264 + ks * 32 + q * 8];

    float bd[8]; int bi[8];
#pragma unroll
    for (int i = 0; i < 8; ++i) { bd[i] = FLT_MAX; bi[i] = 0x7fffffff; }

    const short8* eB = (const short8*)embB;   // row n = 32 short8 chunks
    int nbase = w * 256;
    for (int ns = 0; ns < 16; ++ns) {
        int nrow = nbase + ns * 16 + lm;      // this lane's code column
        float en = enorm[nrow];
        f32x4 a0 = {0.f, 0.f, 0.f, 0.f}, a1 = {0.f, 0.f, 0.f, 0.f};
#pragma unroll
        for (int half = 0; half < 2; ++half) {
            short8 Bv[4];
#pragma unroll
            for (int k2 = 0; k2 < 4; ++k2)
                Bv[k2] = eB[nrow * 32 + (half * 4 + k2) * 4 + q];
#pragma unroll
            for (int k2 = 0; k2 < 4; ++k2) {
                int ks = half * 4 + k2;
                a0 = __builtin_amdgcn_mfma_f32_16x16x32_bf16(A[0][ks], Bv[k2], a0, 0, 0, 0);
                a1 = __builtin_amdgcn_mfma_f32_16x16x32_bf16(A[1][ks], Bv[k2], a1, 0, 0, 0);
            }
        }
#pragma unroll
        for (int r = 0; r < 4; ++r) {
            float d0 = en - 2.f * a0[r];
            if (d0 < bd[r])     { bd[r] = d0;     bi[r] = nrow; }
            float d1 = en - 2.f * a1[r];
            if (d1 < bd[4 + r]) { bd[4 + r] = d1; bi[4 + r] = nrow; }
        }
    }

    // reduce across the 16 code-columns (lanes sharing q)
#pragma unroll
    for (int off = 1; off < 16; off <<= 1) {
#pragma unroll
        for (int i = 0; i < 8; ++i) {
            float od = __shfl_xor(bd[i], off, 64);
            int   oi = __shfl_xor(bi[i], off, 64);
            if (od < bd[i] || (od == bd[i] && oi < bi[i])) { bd[i] = od; bi[i] = oi; }
        }
    }
    if (lm == 0) {
#pragma unroll
        for (int r = 0; r < 4; ++r) {
            rv[w * 32 + q * 4 + r]      = bd[r];     ri[w * 32 + q * 4 + r]      = bi[r];
            rv[w * 32 + 16 + q * 4 + r] = bd[4 + r]; ri[w * 32 + 16 + q * 4 + r] = bi[4 + r];
        }
    }
    __syncthreads();
    if (t < 32) {   // merge the 4 waves' disjoint code ranges (ascending -> tie ok)
        float bv = rv[t]; int bidx = ri[t];
        for (int ww = 1; ww < 4; ++ww) {
            float v = rv[ww * 32 + t]; int ii = ri[ww * 32 + t];
            if (v < bv || (v == bv && ii < bidx)) { bv = v; bidx = ii; }
        }
        idxOut[m0 + t] = bidx;
    }
}

// ---------------------------------------------------------------------------
// R: z_q gather (per-thread, L1-backed) + loss partial + histogram.
// Block = 64 positions x 256 channels; thread = 4 positions x 16 channels.
// ---------------------------------------------------------------------------
__global__ __launch_bounds__(256, 4) void output_kernel(
        const float* __restrict__ z, const float* __restrict__ emb,
        const int* __restrict__ idxArr, float* __restrict__ zq,
        int* __restrict__ hist, float* __restrict__ lossAcc) {
    int t = threadIdx.x;
    int n0 = blockIdx.x * 64;
    int b = n0 >> 10, pb = n0 & 1023;

    if (t < 64) atomicAdd(&hist[idxArr[n0 + t]], 1);

    int p4 = t & 15, cg = t >> 4;
    int4 iv = *(const int4*)&idxArr[n0 + p4 * 4];
    const float* zb  = z  + (size_t)b * BSTRIDE + pb + p4 * 4;
    float*       zqb = zq + (size_t)b * BSTRIDE + pb + p4 * 4;
    const float* e0 = emb + (size_t)iv.x * EDIM;
    const float* e1 = emb + (size_t)iv.y * EDIM;
    const float* e2 = emb + (size_t)iv.z * EDIM;
    const float* e3 = emb + (size_t)iv.w * EDIM;
    float ls = 0.f;
#pragma unroll 4
    for (int cc = 0; cc < 16; ++cc) {
        int c = cg * 16 + cc;
        float4 zv = *(const float4*)&zb[(size_t)c * HW];
        float4 ev;
        ev.x = e0[c]; ev.y = e1[c]; ev.z = e2[c]; ev.w = e3[c];
        *(float4*)&zqb[(size_t)c * HW] = ev;
        float dx = ev.x - zv.x, dy = ev.y - zv.y, dz = ev.z - zv.z, dw = ev.w - zv.w;
        ls += dx * dx + dy * dy + dz * dz + dw * dw;
    }
#pragma unroll
    for (int off = 32; off; off >>= 1) ls += __shfl_down(ls, off, 64);
    if ((t & 63) == 0) atomicAdd(lossAcc, ls);
}

// ---------------------------------------------------------------------------
// F: finalize loss + perplexity into d_out tail.
// ---------------------------------------------------------------------------
__global__ void finalize_kernel(const int* __restrict__ hist,
                                const float* __restrict__ lossAcc,
                                float* __restrict__ out) {
    __shared__ float wsum[4];
    int t = threadIdx.x;
    float s = 0.f;
    for (int j = t; j < NE; j += 256) {
        float p = (float)hist[j] * (1.0f / 32768.0f);
        s += p * logf(p + 1e-10f);
    }
#pragma unroll
    for (int off = 32; off; off >>= 1) s += __shfl_down(s, off, 64);
    if ((t & 63) == 0) wsum[t >> 6] = s;
    __syncthreads();
    if (t == 0) {
        float S = wsum[0] + wsum[1] + wsum[2] + wsum[3];
        out[TOTAL]     = 1.25f * lossAcc[0] / (float)TOTAL;
        out[TOTAL + 1] = expf(-S);
    }
}

extern "C" void kernel_launch(void* const* d_in, const int* in_sizes, int n_in,
                              void* d_out, int out_size, void* d_ws, size_t ws_size,
                              hipStream_t stream) {
    (void)in_sizes; (void)n_in; (void)out_size; (void)ws_size;
    const float* z   = (const float*)d_in[0];
    const float* emb = (const float*)d_in[1];
    float* out = (float*)d_out;
    char* ws = (char*)d_ws;
    unsigned short* embB = (unsigned short*)(ws + EMBB_OFF);
    float* enorm   = (float*)(ws + ENORM_OFF);
    int*   idxArr  = (int*)(ws + IDX_OFF);
    int*   hist    = (int*)(ws + HIST_OFF);
    float* lossAcc = (float*)(ws + LOSS_OFF);

    hipMemsetAsync(ws + HIST_OFF, 0, 4096 + 16, stream);   // hist + loss accum
    prep_emb<<<4, 256, 0, stream>>>(emb, embB, enorm);
    argmin_kernel<<<1024, 256, 0, stream>>>(z, embB, enorm, idxArr);
    output_kernel<<<512, 256, 0, stream>>>(z, emb, idxArr, out, hist, lossAcc);
    finalize_kernel<<<1, 256, 0, stream>>>(hist, lossAcc, out);
}

// Round 3
// 147.181 us; speedup vs baseline: 2.5490x; 1.3572x over previous
//
#include <hip/hip_runtime.h>
#include <cfloat>

typedef __attribute__((ext_vector_type(8))) short short8;
typedef __attribute__((ext_vector_type(4))) float f32x4;

#define NE 1024
#define EDIM 256
#define HW 1024
#define BSTRIDE (EDIM * HW)        // 262144
#define TOTAL 8388608

// workspace layout (bytes)
#define EMBB_OFF  0                        // ushort[1024*256] bf16 = 512 KB
#define ENORM_OFF (512 * 1024)             // float[1024]
#define HIST_OFF  (ENORM_OFF + 4096)       // int[1024]
#define LOSS_OFF  (HIST_OFF + 4096)        // float accumulator

// round-to-nearest-even fp32 -> bf16 bits (inputs are finite)
__device__ __forceinline__ unsigned short f2bf(float x) {
    unsigned u = __builtin_bit_cast(unsigned, x);
    return (unsigned short)((u + 0x7fffu + ((u >> 16) & 1u)) >> 16);
}

// ---------------------------------------------------------------------------
// P: emb fp32 [1024][256] -> embB bf16 rows + enorm. 16 blocks x 256 thr,
// 4 threads per code row (seg = quarter of the row), shfl-reduce the norm.
// ---------------------------------------------------------------------------
__global__ void prep_emb(const float* __restrict__ emb,
                         unsigned short* __restrict__ embB,
                         float* __restrict__ enorm) {
    int gid = blockIdx.x * 256 + threadIdx.x;
    int row = gid >> 2, seg = gid & 3;
    const float4* e4 = (const float4*)(emb + (size_t)row * EDIM) + seg * 16;
    float s = 0.f;
#pragma unroll
    for (int i = 0; i < 8; ++i) {
        float4 a = e4[2 * i], b = e4[2 * i + 1];
        s += a.x * a.x + a.y * a.y + a.z * a.z + a.w * a.w
           + b.x * b.x + b.y * b.y + b.z * b.z + b.w * b.w;
        short8 v;
        v[0] = (short)f2bf(a.x); v[1] = (short)f2bf(a.y);
        v[2] = (short)f2bf(a.z); v[3] = (short)f2bf(a.w);
        v[4] = (short)f2bf(b.x); v[5] = (short)f2bf(b.y);
        v[6] = (short)f2bf(b.z); v[7] = (short)f2bf(b.w);
        *(short8*)&embB[(size_t)row * EDIM + seg * 64 + i * 8] = v;
    }
    s += __shfl_xor(s, 1, 64);
    s += __shfl_xor(s, 2, 64);
    if (seg == 0) enorm[row] = s;
}

// ---------------------------------------------------------------------------
// F: fused argmin + gather + loss + hist. Block = 64 positions, grid 512.
// Waves (mw,nw): mw = 32-position half (2 m-frags, A in regs), nw = 64-code
// half of each 128-code N-tile (B staged in LDS, shared by all waves).
// Epilogue: stage selected fp32 emb rows into LDS [c][p-quad float4 slots],
// write z_q coalesced float4, loss from L2-hot z re-read, hist atomics.
// ---------------------------------------------------------------------------
__global__ __launch_bounds__(256, 2) void fused_kernel(
        const float* __restrict__ z, const float* __restrict__ emb,
        const unsigned short* __restrict__ embB, const float* __restrict__ enormG,
        float* __restrict__ zq, int* __restrict__ hist,
        float* __restrict__ lossAcc) {
    // union buffer: As 64x264 bf16 (33.8 KB) / Bs 128x264 bf16 (67.6 KB)
    //             / Es 256x17 float4 (69.6 KB)
    __shared__ __align__(16) char smem[256 * 17 * 16];
    __shared__ float Ens[NE];
    __shared__ float rv[2][64];
    __shared__ int   ri[2][64];
    __shared__ int   idxm[64];

    unsigned short* As = (unsigned short*)smem;
    unsigned short* Bs = (unsigned short*)smem;
    short8*        Bs8 = (short8*)smem;
    float4*         Es = (float4*)smem;
    float*         Esf = (float*)smem;

    int t = threadIdx.x;
    int m0 = blockIdx.x * 64;
    int b = m0 >> 10, pb = m0 & 1023;
    const float* zb  = z  + (size_t)b * BSTRIDE + pb;
    float*       zqb = zq + (size_t)b * BSTRIDE + pb;

    for (int j = t; j < NE; j += 256) Ens[j] = enormG[j];

    {   // stage A: 64 positions x 256 channels, bf16, transposed to [p][c]
        int p = t & 63, cg = t >> 6;
        const float* zp = zb + p;
        for (int cc = 0; cc < 64; ++cc) {
            int c = cg * 64 + cc;
            As[p * 264 + c] = f2bf(zp[(size_t)c * HW]);
        }
    }
    __syncthreads();

    int w = t >> 6, l = t & 63, lm = l & 15, q = l >> 4;
    int mw = w >> 1, nw = w & 1;

    short8 A[2][8];
#pragma unroll
    for (int s = 0; s < 2; ++s)
#pragma unroll
        for (int ks = 0; ks < 8; ++ks)
            A[s][ks] = *(const short8*)&As[(mw * 32 + s * 16 + lm) * 264 + ks * 32 + q * 8];

    float bd[8]; int bi[8];
#pragma unroll
    for (int i = 0; i < 8; ++i) { bd[i] = FLT_MAX; bi[i] = 0x7fffffff; }

    __syncthreads();   // A consumed; smem becomes the B tile buffer

    const short8* eB8 = (const short8*)embB;
    for (int nt = 0; nt < 8; ++nt) {
        int n0 = nt * 128;
        // stage B tile: 128 code rows x 256 k, coalesced 1KB/wave-instr
#pragma unroll
        for (int i = 0; i < 16; ++i) {
            int ch = i * 256 + t;
            int row = ch >> 5, k8 = ch & 31;
            Bs8[row * 33 + k8] = eB8[(size_t)(n0 + row) * 32 + k8];
        }
        __syncthreads();
#pragma unroll
        for (int nf = 0; nf < 4; ++nf) {
            int cl = nw * 64 + nf * 16 + lm;      // local code row in tile
            float en = Ens[n0 + cl];
            f32x4 a0a = {0,0,0,0}, a0b = {0,0,0,0};
            f32x4 a1a = {0,0,0,0}, a1b = {0,0,0,0};
#pragma unroll
            for (int ks = 0; ks < 8; ks += 2) {
                short8 Bv0 = *(const short8*)&Bs[cl * 264 + ks * 32 + q * 8];
                short8 Bv1 = *(const short8*)&Bs[cl * 264 + (ks + 1) * 32 + q * 8];
                a0a = __builtin_amdgcn_mfma_f32_16x16x32_bf16(A[0][ks],     Bv0, a0a, 0, 0, 0);
                a1a = __builtin_amdgcn_mfma_f32_16x16x32_bf16(A[1][ks],     Bv0, a1a, 0, 0, 0);
                a0b = __builtin_amdgcn_mfma_f32_16x16x32_bf16(A[0][ks + 1], Bv1, a0b, 0, 0, 0);
                a1b = __builtin_amdgcn_mfma_f32_16x16x32_bf16(A[1][ks + 1], Bv1, a1b, 0, 0, 0);
            }
            int code = n0 + cl;
#pragma unroll
            for (int r = 0; r < 4; ++r) {
                float d0 = en - 2.f * (a0a[r] + a0b[r]);
                if (d0 < bd[r])     { bd[r] = d0;     bi[r] = code; }
                float d1 = en - 2.f * (a1a[r] + a1b[r]);
                if (d1 < bd[4 + r]) { bd[4 + r] = d1; bi[4 + r] = code; }
            }
        }
        __syncthreads();   // B tile consumed
    }

    // reduce across the 16 code-columns (lanes sharing q)
#pragma unroll
    for (int off = 1; off < 16; off <<= 1) {
#pragma unroll
        for (int i = 0; i < 8; ++i) {
            float od = __shfl_xor(bd[i], off, 64);
            int   oi = __shfl_xor(bi[i], off, 64);
            if (od < bd[i] || (od == bd[i] && oi < bi[i])) { bd[i] = od; bi[i] = oi; }
        }
    }
    if (lm == 0) {
#pragma unroll
        for (int s = 0; s < 2; ++s)
#pragma unroll
            for (int r = 0; r < 4; ++r) {
                int p = mw * 32 + s * 16 + q * 4 + r;
                rv[nw][p] = bd[s * 4 + r];
                ri[nw][p] = bi[s * 4 + r];
            }
    }
    __syncthreads();
    if (t < 64) {
        float v0 = rv[0][t]; int i0 = ri[0][t];
        float v1 = rv[1][t]; int i1 = ri[1][t];
        int best = (v1 < v0 || (v1 == v0 && i1 < i0)) ? i1 : i0;
        idxm[t] = best;
        atomicAdd(&hist[best], 1);
    }
    __syncthreads();

    {   // stage selected fp32 emb rows: position r, quarter qo
        int r = t >> 2, qo = t & 3;
        int kr = idxm[r];
        const float4* er = (const float4*)(emb + (size_t)kr * EDIM);
        int base = (r >> 2) * 4 + (r & 3);     // dword offset within c-row
#pragma unroll
        for (int u = 0; u < 16; ++u) {
            float4 v = er[qo * 16 + u];
            int c = (qo * 16 + u) * 4;
            Esf[(c + 0) * 68 + base] = v.x;
            Esf[(c + 1) * 68 + base] = v.y;
            Esf[(c + 2) * 68 + base] = v.z;
            Esf[(c + 3) * 68 + base] = v.w;
        }
    }
    __syncthreads();

    {   // z_q write + loss: thread = (p-quad, 16 channels)
        int pq = t & 15, cg2 = t >> 4;
        float ls = 0.f;
#pragma unroll 4
        for (int cc = 0; cc < 16; ++cc) {
            int c = cg2 * 16 + cc;
            float4 zv = *(const float4*)&zb[(size_t)c * HW + pq * 4];
            float4 ev = Es[c * 17 + pq];
            *(float4*)&zqb[(size_t)c * HW + pq * 4] = ev;
            float dx = ev.x - zv.x, dy = ev.y - zv.y;
            float dz = ev.z - zv.z, dw = ev.w - zv.w;
            ls += dx * dx + dy * dy + dz * dz + dw * dw;
        }
#pragma unroll
        for (int off = 32; off; off >>= 1) ls += __shfl_down(ls, off, 64);
        if ((t & 63) == 0) atomicAdd(lossAcc, ls);
    }
}

// ---------------------------------------------------------------------------
// Z: finalize loss + perplexity into d_out tail.
// ---------------------------------------------------------------------------
__global__ void finalize_kernel(const int* __restrict__ hist,
                                const float* __restrict__ lossAcc,
                                float* __restrict__ out) {
    __shared__ float wsum[4];
    int t = threadIdx.x;
    float s = 0.f;
    for (int j = t; j < NE; j += 256) {
        float p = (float)hist[j] * (1.0f / 32768.0f);
        s += p * logf(p + 1e-10f);
    }
#pragma unroll
    for (int off = 32; off; off >>= 1) s += __shfl_down(s, off, 64);
    if ((t & 63) == 0) wsum[t >> 6] = s;
    __syncthreads();
    if (t == 0) {
        float S = wsum[0] + wsum[1] + wsum[2] + wsum[3];
        out[TOTAL]     = 1.25f * lossAcc[0] / (float)TOTAL;
        out[TOTAL + 1] = expf(-S);
    }
}

extern "C" void kernel_launch(void* const* d_in, const int* in_sizes, int n_in,
                              void* d_out, int out_size, void* d_ws, size_t ws_size,
                              hipStream_t stream) {
    (void)in_sizes; (void)n_in; (void)out_size; (void)ws_size;
    const float* z   = (const float*)d_in[0];
    const float* emb = (const float*)d_in[1];
    float* out = (float*)d_out;
    char* ws = (char*)d_ws;
    unsigned short* embB = (unsigned short*)(ws + EMBB_OFF);
    float* enorm   = (float*)(ws + ENORM_OFF);
    int*   hist    = (int*)(ws + HIST_OFF);
    float* lossAcc = (float*)(ws + LOSS_OFF);

    hipMemsetAsync(ws + HIST_OFF, 0, 4096 + 16, stream);   // hist + loss accum
    prep_emb<<<16, 256, 0, stream>>>(emb, embB, enorm);
    fused_kernel<<<512, 256, 0, stream>>>(z, emb, embB, enorm, out, hist, lossAcc);
    finalize_kernel<<<1, 256, 0, stream>>>(hist, lossAcc, out);
}